// Round 1
// baseline (4435.490 us; speedup 1.0000x reference)
//
#include <hip/hip_runtime.h>

#define NB 2048      // batches
#define NP 32        // particles per batch
#define ND 6         // action dim
#define NOBS 17      // obs dim
#define NH 256       // hidden
#define NSTEPS 10
#define C_LR 0.1f
#define C_LIM 1.0f
#define C_LOGNP1 3.4965075614664802f   // float32(log(33))

// One workgroup per batch. 256 threads = 4 waves.
// Thread tile: sy = t>>6 (wave id) -> samples s0=8*sy .. +7 ; jx = t&63 -> cols j0=4*jx .. +3
__global__ __launch_bounds__(256, 2)
void svgd_kernel(const float* __restrict__ obs, const float* __restrict__ a_in,
                 const float* __restrict__ W1, const float* __restrict__ b1,
                 const float* __restrict__ W2, const float* __restrict__ b2,
                 const float* __restrict__ W3, float* __restrict__ out)
{
    __shared__ float wstage[16 * NH];   // 16KB  W2 chunk (fwd: 16 rows; bwd: 16 cols transposed)
    __shared__ float hb[NP * NH];       // 32KB  h1, then dh2_pre
    __shared__ float ds_[NP * NP];      // 4KB   dist_sq (also obs staging at init)
    __shared__ float ps_[512];          // 2KB   unique pair distances (496 used)
    __shared__ float sc_[NP * 8];       // score (s) per particle
    __shared__ float Xs[NP * 8];        // current X
    __shared__ float phiA[NP * 8];      // phi[0..5], l4 partial [6], l5 partial [7]
    __shared__ float logp_s[NP];
    __shared__ float med_s;

    const int t  = threadIdx.x;
    const int b  = blockIdx.x;
    const int jx = t & 63;
    const int sy = t >> 6;
    const int j0 = jx * 4;
    const int s0 = sy * 8;

    // ---- init: stage obs (into ds_ temp) and X; zero logp ----
    const float* obs_g = obs + b * (NP * NOBS);
    for (int p = t; p < NP * NOBS; p += 256) ds_[p] = obs_g[p];
    const float* a_g = a_in + b * (NP * ND);
    if (t < NP * ND) { int s = t / ND; int d = t - s * ND; Xs[s * 8 + d] = a_g[t]; }
    if (t < NP) logp_s[t] = 0.0f;
    __syncthreads();

    // ---- step-invariant register preloads ----
    float W1xr[ND][4];
#pragma unroll
    for (int d = 0; d < ND; ++d) {
        const float4 w = *(const float4*)(W1 + (NOBS + d) * NH + j0);
        W1xr[d][0] = w.x; W1xr[d][1] = w.y; W1xr[d][2] = w.z; W1xr[d][3] = w.w;
    }
    const float4 b2r4 = *(const float4*)(b2 + j0);
    const float b2r[4] = { b2r4.x, b2r4.y, b2r4.z, b2r4.w };
    const float4 w3r4 = *(const float4*)(W3 + j0);
    const float W3r[4] = { w3r4.x, w3r4.y, w3r4.z, w3r4.w };

    // c1 = obs @ W1[:17] + b1  (step-invariant), kept in registers
    float c1[8][4];
    {
        const float4 b1r = *(const float4*)(b1 + j0);
#pragma unroll
        for (int ss = 0; ss < 8; ++ss) {
            c1[ss][0] = b1r.x; c1[ss][1] = b1r.y; c1[ss][2] = b1r.z; c1[ss][3] = b1r.w;
        }
        for (int k = 0; k < NOBS; ++k) {
            const float4 w = *(const float4*)(W1 + k * NH + j0);
#pragma unroll
            for (int ss = 0; ss < 8; ++ss) {
                const float o = ds_[(s0 + ss) * NOBS + k];
                c1[ss][0] += o * w.x; c1[ss][1] += o * w.y;
                c1[ss][2] += o * w.z; c1[ss][3] += o * w.w;
            }
        }
    }
    __syncthreads();  // done using ds_ as obs buffer

    for (int step = 0; step < NSTEPS; ++step) {
        // ---- phase 1: h1 = relu(c1 + X @ W1x), keep mask bits ----
        unsigned mask1 = 0u;
#pragma unroll
        for (int ss = 0; ss < 8; ++ss) {
            float h0 = c1[ss][0], h1v = c1[ss][1], h2v = c1[ss][2], h3 = c1[ss][3];
#pragma unroll
            for (int d = 0; d < ND; ++d) {
                const float xv = Xs[(s0 + ss) * 8 + d];
                h0 += xv * W1xr[d][0]; h1v += xv * W1xr[d][1];
                h2v += xv * W1xr[d][2]; h3 += xv * W1xr[d][3];
            }
            mask1 |= ((unsigned)(h0 > 0.0f)) << (ss * 4 + 0);
            mask1 |= ((unsigned)(h1v > 0.0f)) << (ss * 4 + 1);
            mask1 |= ((unsigned)(h2v > 0.0f)) << (ss * 4 + 2);
            mask1 |= ((unsigned)(h3 > 0.0f)) << (ss * 4 + 3);
            float4 hr;
            hr.x = fmaxf(h0, 0.0f); hr.y = fmaxf(h1v, 0.0f);
            hr.z = fmaxf(h2v, 0.0f); hr.w = fmaxf(h3, 0.0f);
            *(float4*)(hb + (s0 + ss) * NH + j0) = hr;
        }

        // ---- phase 2: fwd GEMM  h2_pre = h1 @ W2 + b2 ----
        float acc[8][4];
#pragma unroll
        for (int ss = 0; ss < 8; ++ss) {
            acc[ss][0] = b2r[0]; acc[ss][1] = b2r[1]; acc[ss][2] = b2r[2]; acc[ss][3] = b2r[3];
        }
        for (int kt = 0; kt < 16; ++kt) {
            __syncthreads();
            {   // stage rows kt*16..+15 (contiguous 16KB), coalesced float4
                const float4* g = (const float4*)(W2 + kt * 16 * NH);
                float4* l = (float4*)wstage;
#pragma unroll
                for (int m = 0; m < 4; ++m) l[t + 256 * m] = g[t + 256 * m];
            }
            __syncthreads();
#pragma unroll
            for (int i = 0; i < 16; ++i) {
                const float4 w = *(const float4*)(wstage + i * NH + j0);
                const int ib = kt * 16 + i;
#pragma unroll
                for (int ss = 0; ss < 8; ++ss) {
                    const float hv = hb[(s0 + ss) * NH + ib];
                    acc[ss][0] += hv * w.x; acc[ss][1] += hv * w.y;
                    acc[ss][2] += hv * w.z; acc[ss][3] += hv * w.w;
                }
            }
        }
        __syncthreads();

        // ---- phase 3: dh2_pre = W3 * (h2_pre > 0) -> hb ----
#pragma unroll
        for (int ss = 0; ss < 8; ++ss) {
            float4 dv;
            dv.x = acc[ss][0] > 0.0f ? W3r[0] : 0.0f;
            dv.y = acc[ss][1] > 0.0f ? W3r[1] : 0.0f;
            dv.z = acc[ss][2] > 0.0f ? W3r[2] : 0.0f;
            dv.w = acc[ss][3] > 0.0f ? W3r[3] : 0.0f;
            *(float4*)(hb + (s0 + ss) * NH + j0) = dv;
        }

        // ---- phase 4: bwd GEMM  dh1 = dh2_pre @ W2^T ----
        float acc2[8][4];
#pragma unroll
        for (int ss = 0; ss < 8; ++ss) { acc2[ss][0] = 0; acc2[ss][1] = 0; acc2[ss][2] = 0; acc2[ss][3] = 0; }
        for (int jc = 0; jc < 16; ++jc) {
            __syncthreads();
            {   // stage cols jc*16..+15 transposed: wstage[jj][i] = W2[i][jc*16+jj]
                const float* g = W2 + t * NH + jc * 16;
                const float4 q0 = ((const float4*)g)[0];
                const float4 q1 = ((const float4*)g)[1];
                const float4 q2 = ((const float4*)g)[2];
                const float4 q3 = ((const float4*)g)[3];
                wstage[ 0 * NH + t] = q0.x; wstage[ 1 * NH + t] = q0.y;
                wstage[ 2 * NH + t] = q0.z; wstage[ 3 * NH + t] = q0.w;
                wstage[ 4 * NH + t] = q1.x; wstage[ 5 * NH + t] = q1.y;
                wstage[ 6 * NH + t] = q1.z; wstage[ 7 * NH + t] = q1.w;
                wstage[ 8 * NH + t] = q2.x; wstage[ 9 * NH + t] = q2.y;
                wstage[10 * NH + t] = q2.z; wstage[11 * NH + t] = q2.w;
                wstage[12 * NH + t] = q3.x; wstage[13 * NH + t] = q3.y;
                wstage[14 * NH + t] = q3.z; wstage[15 * NH + t] = q3.w;
            }
            __syncthreads();
#pragma unroll
            for (int j = 0; j < 16; ++j) {
                const float4 w = *(const float4*)(wstage + j * NH + j0);
                const int jb = jc * 16 + j;
#pragma unroll
                for (int ss = 0; ss < 8; ++ss) {
                    const float dv = hb[(s0 + ss) * NH + jb];
                    acc2[ss][0] += dv * w.x; acc2[ss][1] += dv * w.y;
                    acc2[ss][2] += dv * w.z; acc2[ss][3] += dv * w.w;
                }
            }
        }

        // ---- phase 5: score = (dh1 * mask1) @ W1x^T, wave-reduce over 64 lanes ----
#pragma unroll
        for (int ss = 0; ss < 8; ++ss) {
            float dp[4];
#pragma unroll
            for (int k = 0; k < 4; ++k)
                dp[k] = ((mask1 >> (ss * 4 + k)) & 1u) ? acc2[ss][k] : 0.0f;
#pragma unroll
            for (int d = 0; d < ND; ++d) {
                float v = dp[0] * W1xr[d][0] + dp[1] * W1xr[d][1]
                        + dp[2] * W1xr[d][2] + dp[3] * W1xr[d][3];
                v += __shfl_xor(v, 32); v += __shfl_xor(v, 16); v += __shfl_xor(v, 8);
                v += __shfl_xor(v, 4);  v += __shfl_xor(v, 2);  v += __shfl_xor(v, 1);
                if (jx == 0) sc_[(s0 + ss) * 8 + d] = v;
            }
        }
        __syncthreads();

        // ---- phase 6: dist_sq (full 32x32) ----
#pragma unroll
        for (int m = 0; m < 4; ++m) {
            const int p = t + 256 * m;
            const int i = p >> 5, j = p & 31;
            float s = 0.0f;
#pragma unroll
            for (int d = 0; d < ND; ++d) {
                const float df = Xs[i * 8 + d] - Xs[j * 8 + d];
                s += df * df;
            }
            ds_[p] = s;
        }
        __syncthreads();

        // ---- phase 7: unique pair list (i<j), 496 values ----
        for (int p = t; p < 496; p += 256) {
            int rem = p, i = 0;
            while (rem >= 31 - i) { rem -= 31 - i; ++i; }
            const int j = i + 1 + rem;
            ps_[p] = ds_[i * 32 + j];
        }
        __syncthreads();

        // ---- phase 8: exact median (rank 511 of 1024) by counting selection ----
        // full-array counts: less(v) = 32*(v>0) + 2*pl(v);  leq(v) = 32 + 2*ple(v)
        {
            const float cv0 = ps_[t];
            const float cv1 = (t < 240) ? ps_[t + 256] : 0.0f;
            int c0l = 0, c0e = 0, c1l = 0, c1e = 0;
#pragma unroll 4
            for (int u = 0; u < 496; ++u) {
                const float dv = ps_[u];
                c0l += dv < cv0; c0e += dv <= cv0;
                c1l += dv < cv1; c1e += dv <= cv1;
            }
            int l = 2 * c0l + (cv0 > 0.0f ? 32 : 0);
            int e = 2 * c0e + 32;
            if (l <= 511 && 511 < e) med_s = cv0;
            l = 2 * c1l + (cv1 > 0.0f ? 32 : 0);
            e = 2 * c1e + 32;
            if (l <= 511 && 511 < e) med_s = cv1;
        }
        phiA[t] = 0.0f;   // zero phi/l4/l5 accumulators (exactly 256 slots)
        __syncthreads();

        const float med = med_s;
        const float gam = 1.0f / (1e-8f + med / C_LOGNP1);  // == 1/(1e-8 + 2*(med/(2*L)))

        // ---- phase 9: phi, line_4, line_5 partials (thread: i = t&31, 4 j's) ----
        {
            const int i = t & 31, jg = t >> 5;
            float ph[ND] = {0, 0, 0, 0, 0, 0};
            float l4p = 0.0f, l5p = 0.0f;
#pragma unroll
            for (int jj = 0; jj < 4; ++jj) {
                const int j = jg * 4 + jj;
                const float dsv = ds_[i * 32 + j];
                const float kap = __expf(-gam * dsv);
                const float tg = 2.0f * gam * kap;   // -kappa_grad = tg * diff
                float dot = 0.0f;
#pragma unroll
                for (int d = 0; d < ND; ++d) {
                    const float df = Xs[i * 8 + d] - Xs[j * 8 + d];
                    const float sj = sc_[j * 8 + d];
                    ph[d] += kap * sj + tg * df;
                    dot += df * sj;
                }
                l4p += -tg * dot;                    // sum_d kappa_grad * s[j]
                l5p += tg * dsv - 6.0f * kap;        // 2g*dsq*kap - D*kap
            }
#pragma unroll
            for (int d = 0; d < ND; ++d) atomicAdd(&phiA[i * 8 + d], ph[d]);
            atomicAdd(&phiA[i * 8 + 6], l4p);
            atomicAdd(&phiA[i * 8 + 7], l5p);
        }
        __syncthreads();

        // ---- phase 10: updates ----
        if (t < NP * ND) {
            const int i = t / ND, d = t - i * ND;
            const float phiv = phiA[i * 8 + d] * (1.0f / 32.0f);
            float x = Xs[i * 8 + d] + C_LR * phiv;
            x = fminf(fmaxf(x, -C_LIM), C_LIM);
            Xs[i * 8 + d] = x;
        } else if (t < NP * ND + NP) {
            const int i = t - NP * ND;
            const float l4 = phiA[i * 8 + 6] * (1.0f / 32.0f);
            const float l5 = -2.0f * gam * (phiA[i * 8 + 7] * (1.0f / 32.0f));
            logp_s[i] -= C_LR * (l4 + l5);
        }
        __syncthreads();
    }

    // ---- output: a (B*N, D) then logp (B, N), both fp32 flat ----
    if (t < NP * ND) out[b * (NP * ND) + t] = Xs[(t / ND) * 8 + (t % ND)];
    if (t < NP) out[NB * NP * ND + b * NP + t] = logp_s[t];
}

extern "C" void kernel_launch(void* const* d_in, const int* in_sizes, int n_in,
                              void* d_out, int out_size, void* d_ws, size_t ws_size,
                              hipStream_t stream) {
    const float* obs = (const float*)d_in[0];
    const float* a   = (const float*)d_in[1];
    const float* W1  = (const float*)d_in[2];
    const float* b1  = (const float*)d_in[3];
    const float* W2  = (const float*)d_in[4];
    const float* b2  = (const float*)d_in[5];
    const float* W3  = (const float*)d_in[6];
    // d_in[7] = b3: unused (constant offset, drops out of grad; q-values never output)
    float* out = (float*)d_out;
    svgd_kernel<<<NB, 256, 0, stream>>>(obs, a, W1, b1, W2, b2, W3, out);
}

// Round 2
// 1248.609 us; speedup vs baseline: 3.5523x; 3.5523x over previous
//
#include <hip/hip_runtime.h>
#include <hip/hip_bf16.h>

#define NB 2048      // batches
#define NP 32        // particles per batch
#define ND 6         // action dim
#define NOBS 17      // obs dim
#define NH 256       // hidden
#define NSTEPS 10
#define C_LR 0.1f
#define C_LIM 1.0f
#define C_LOGNP1 3.4965075614664802f   // float32(log(33))

typedef __bf16 bf16x8 __attribute__((ext_vector_type(8)));
typedef float  f32x4  __attribute__((ext_vector_type(4)));

#define MFMA(a, b, c) __builtin_amdgcn_mfma_f32_16x16x32_bf16(a, b, c, 0, 0, 0)

// fp32 -> bf16 bits, round-to-nearest-even (finite inputs)
static __device__ __forceinline__ unsigned short f2bf(float f) {
    union { float f; unsigned u; } c; c.f = f;
    const unsigned r = c.u + 0x7fffu + ((c.u >> 16) & 1u);
    return (unsigned short)(r >> 16);
}

// ---------------------------------------------------------------------------
// Prep: build B-fragment-swizzled bf16 copies of W2, W2^T, W1x^T in d_ws.
// Fragment (kt,nt) of a 256x256 B operand: lane l, elem j ->
//   B[kt*32 + (l>>4)*8 + j][nt*16 + (l&15)], stored contiguous per lane (16B).
//   ws[0      ..65535]  : W2   as B (fwd:  h2 = h1 @ W2)
//   ws[65536  ..131071] : W2^T as B (bwd:  dh1 = dh2 @ W2^T)
//   ws[131072 ..135167] : W1x^T (256x16, cols>=6 zero) as B (score GEMM)
// ---------------------------------------------------------------------------
__global__ void prep_swizzle(const float* __restrict__ W1, const float* __restrict__ W2,
                             unsigned short* __restrict__ ws) {
    const int g = blockIdx.x * 256 + threadIdx.x;
    unsigned short v[8];
    if (g < 8192) {
        const int l = g & 63, fid = g >> 6;
        const int kt = fid >> 4, nt = fid & 15;
        const int row0 = kt * 32 + (l >> 4) * 8;
        const int col  = nt * 16 + (l & 15);
#pragma unroll
        for (int j = 0; j < 8; ++j) v[j] = f2bf(W2[(row0 + j) * NH + col]);
        ushort4* dst = (ushort4*)(ws + (size_t)g * 8);
        dst[0] = make_ushort4(v[0], v[1], v[2], v[3]);
        dst[1] = make_ushort4(v[4], v[5], v[6], v[7]);
    } else if (g < 16384) {
        const int e = g - 8192;
        const int l = e & 63, fid = e >> 6;
        const int kt = fid >> 4, nt = fid & 15;
        const int row  = nt * 16 + (l & 15);        // W2^T[k][n] = W2[n][k]
        const int col0 = kt * 32 + (l >> 4) * 8;
#pragma unroll
        for (int j = 0; j < 8; ++j) v[j] = f2bf(W2[row * NH + col0 + j]);
        ushort4* dst = (ushort4*)(ws + 65536 + (size_t)e * 8);
        dst[0] = make_ushort4(v[0], v[1], v[2], v[3]);
        dst[1] = make_ushort4(v[4], v[5], v[6], v[7]);
    } else if (g < 16896) {
        const int e = g - 16384;
        const int l = e & 63, kt = e >> 6;
        const int n  = l & 15;
        const int k0 = kt * 32 + (l >> 4) * 8;
#pragma unroll
        for (int j = 0; j < 8; ++j)
            v[j] = (n < ND) ? f2bf(W1[(NOBS + n) * NH + k0 + j]) : (unsigned short)0;
        ushort4* dst = (ushort4*)(ws + 131072 + (size_t)e * 8);
        dst[0] = make_ushort4(v[0], v[1], v[2], v[3]);
        dst[1] = make_ushort4(v[4], v[5], v[6], v[7]);
    }
}

// ---------------------------------------------------------------------------
// Main kernel: one WG per batch, 256 threads = 4 waves.
// A-fragment LDS layout for a 32x256 matrix M[s][c]:
//   fid = (c>>5)*2 + (s>>4); lane = ((c>>3)&3)*16 + (s&15); j = c&7
//   addr(ushorts) = fid*512 + lane*8 + j
// ---------------------------------------------------------------------------
__global__ __launch_bounds__(256, 3)
void svgd_kernel(const float* __restrict__ obs, const float* __restrict__ a_in,
                 const float* __restrict__ W1, const float* __restrict__ b1,
                 const float* __restrict__ W2, const float* __restrict__ b2,
                 const float* __restrict__ W3, const unsigned short* __restrict__ ws,
                 float* __restrict__ out)
{
    __shared__ __attribute__((aligned(16))) unsigned short hA[NP * NH]; // 16KB h1 bf16 (A-layout)
    __shared__ __attribute__((aligned(16))) unsigned short dA[NP * NH]; // 16KB dh2 / dh1*mask
    __shared__ float ds_[NP * NP];      // 4KB dist_sq (obs staging at init)
    __shared__ __attribute__((aligned(16))) float ps_[512]; // 2KB pair distances (496)
    __shared__ float b2s[NH], W3s[NH];  // 2KB
    __shared__ float sc_[NP * 8];       // score
    __shared__ float Xs[NP * 8];        // current X
    __shared__ float phiA[NP * 8];      // phi[0..5], l4 [6], l5 [7]
    __shared__ float logp_s[NP];
    __shared__ float med_s;

    const int t    = threadIdx.x;
    const int b    = blockIdx.x;
    const int lane = t & 63;
    const int w4   = (t >> 6) * 4;      // this wave's first nt
    const int quad = lane >> 4;
    const int jx = t & 63;              // phase-1 col group
    const int sy = t >> 6;
    const int j0 = jx * 4;
    const int s0 = sy * 8;

    const unsigned short* gW2f = ws;
    const unsigned short* gW2b = ws + 65536;
    const unsigned short* gW1p = ws + 131072;

    // ---- init ----
    const float* obs_g = obs + b * (NP * NOBS);
    for (int p = t; p < NP * NOBS; p += 256) ds_[p] = obs_g[p];
    const float* a_g = a_in + b * (NP * ND);
    if (t < NP * ND) { int s = t / ND; int d = t - s * ND; Xs[s * 8 + d] = a_g[t]; }
    if (t < NP) logp_s[t] = 0.0f;
    b2s[t] = b2[t];
    W3s[t] = W3[t];
    __syncthreads();

    // ---- step-invariant register preloads ----
    float W1xr[ND][4];
#pragma unroll
    for (int d = 0; d < ND; ++d) {
        const float4 w = *(const float4*)(W1 + (NOBS + d) * NH + j0);
        W1xr[d][0] = w.x; W1xr[d][1] = w.y; W1xr[d][2] = w.z; W1xr[d][3] = w.w;
    }
    // c1 = obs @ W1[:17] + b1  (step-invariant)
    float c1[8][4];
    {
        const float4 b1r = *(const float4*)(b1 + j0);
#pragma unroll
        for (int ss = 0; ss < 8; ++ss) {
            c1[ss][0] = b1r.x; c1[ss][1] = b1r.y; c1[ss][2] = b1r.z; c1[ss][3] = b1r.w;
        }
        for (int k = 0; k < NOBS; ++k) {
            const float4 w = *(const float4*)(W1 + k * NH + j0);
#pragma unroll
            for (int ss = 0; ss < 8; ++ss) {
                const float o = ds_[(s0 + ss) * NOBS + k];
                c1[ss][0] += o * w.x; c1[ss][1] += o * w.y;
                c1[ss][2] += o * w.z; c1[ss][3] += o * w.w;
            }
        }
    }
    __syncthreads();  // done using ds_ as obs buffer

    for (int step = 0; step < NSTEPS; ++step) {
        // ---- phase 1: h1 = relu(c1 + X @ W1x) -> hA bf16 (A-layout) ----
#pragma unroll
        for (int ss = 0; ss < 8; ++ss) {
            const int s = s0 + ss;
            float h0 = c1[ss][0], h1v = c1[ss][1], h2v = c1[ss][2], h3 = c1[ss][3];
#pragma unroll
            for (int d = 0; d < ND; ++d) {
                const float xv = Xs[s * 8 + d];
                h0 += xv * W1xr[d][0]; h1v += xv * W1xr[d][1];
                h2v += xv * W1xr[d][2]; h3 += xv * W1xr[d][3];
            }
            const int fid = (j0 >> 5) * 2 + (s >> 4);
            const int lp  = ((j0 >> 3) & 3) * 16 + (s & 15);
            *(ushort4*)&hA[fid * 512 + lp * 8 + (j0 & 7)] =
                make_ushort4(f2bf(fmaxf(h0, 0.f)), f2bf(fmaxf(h1v, 0.f)),
                             f2bf(fmaxf(h2v, 0.f)), f2bf(fmaxf(h3, 0.f)));
        }
        __syncthreads();  // S1

        // ---- phase 2: fwd GEMM h2_pre = h1 @ W2 (MFMA), wave w: nt = w4..w4+3 ----
        f32x4 acc[2][4];
        const f32x4 zv = {0.f, 0.f, 0.f, 0.f};
#pragma unroll
        for (int mt = 0; mt < 2; ++mt)
#pragma unroll
            for (int q = 0; q < 4; ++q) acc[mt][q] = zv;
#pragma unroll 2
        for (int kt = 0; kt < 8; ++kt) {
            const bf16x8 a0 = *(const bf16x8*)&hA[(kt * 2 + 0) * 512 + lane * 8];
            const bf16x8 a1 = *(const bf16x8*)&hA[(kt * 2 + 1) * 512 + lane * 8];
#pragma unroll
            for (int q = 0; q < 4; ++q) {
                const bf16x8 bf = *(const bf16x8*)(gW2f + ((kt * 16 + w4 + q) * 64 + lane) * 8);
                acc[0][q] = MFMA(a0, bf, acc[0][q]);
                acc[1][q] = MFMA(a1, bf, acc[1][q]);
            }
        }
        // dh2 = (h2_pre + b2 > 0) ? W3 : 0  -> dA (A-layout, scalar u16 writes)
#pragma unroll
        for (int q = 0; q < 4; ++q) {
            const int n = (w4 + q) * 16 + (lane & 15);
            const float b2v = b2s[n];
            const unsigned short w3v = f2bf(W3s[n]);
            const int base = ((n >> 5) * 2) * 512 + (((n >> 3) & 3) * 16) * 8 + (n & 7);
#pragma unroll
            for (int mt = 0; mt < 2; ++mt)
#pragma unroll
                for (int reg = 0; reg < 4; ++reg) {
                    const float hp = acc[mt][q][reg] + b2v;
                    dA[base + mt * 512 + (quad * 4 + reg) * 8] =
                        (hp > 0.f) ? w3v : (unsigned short)0;
                }
        }
        __syncthreads();  // S2

        // ---- phase 3: bwd GEMM dh1 = dh2 @ W2^T (MFMA) ----
        f32x4 acc2[2][4];
#pragma unroll
        for (int mt = 0; mt < 2; ++mt)
#pragma unroll
            for (int q = 0; q < 4; ++q) acc2[mt][q] = zv;
#pragma unroll 2
        for (int kt = 0; kt < 8; ++kt) {
            const bf16x8 a0 = *(const bf16x8*)&dA[(kt * 2 + 0) * 512 + lane * 8];
            const bf16x8 a1 = *(const bf16x8*)&dA[(kt * 2 + 1) * 512 + lane * 8];
#pragma unroll
            for (int q = 0; q < 4; ++q) {
                const bf16x8 bf = *(const bf16x8*)(gW2b + ((kt * 16 + w4 + q) * 64 + lane) * 8);
                acc2[0][q] = MFMA(a0, bf, acc2[0][q]);
                acc2[1][q] = MFMA(a1, bf, acc2[1][q]);
            }
        }
        __syncthreads();  // S3: all waves done reading dA as dh2

        // ---- phase 4: dA <- dh1 * mask1 (mask = h1 bf16 != 0) ----
#pragma unroll
        for (int q = 0; q < 4; ++q) {
            const int r = (w4 + q) * 16 + (lane & 15);
            const int base = ((r >> 5) * 2) * 512 + (((r >> 3) & 3) * 16) * 8 + (r & 7);
#pragma unroll
            for (int mt = 0; mt < 2; ++mt)
#pragma unroll
                for (int reg = 0; reg < 4; ++reg) {
                    const int idx = base + mt * 512 + (quad * 4 + reg) * 8;
                    const unsigned short hu = hA[idx];
                    dA[idx] = hu ? f2bf(acc2[mt][q][reg]) : (unsigned short)0;
                }
        }
        __syncthreads();  // S4

        // ---- phase 5: score GEMM s = (dh1*mask) @ W1x^T (redundant per wave) ----
        {
            f32x4 sa0 = zv, sa1 = zv;
#pragma unroll
            for (int kt = 0; kt < 8; ++kt) {
                const bf16x8 a0 = *(const bf16x8*)&dA[(kt * 2 + 0) * 512 + lane * 8];
                const bf16x8 a1 = *(const bf16x8*)&dA[(kt * 2 + 1) * 512 + lane * 8];
                const bf16x8 bw = *(const bf16x8*)(gW1p + (kt * 64 + lane) * 8);
                sa0 = MFMA(a0, bw, sa0);
                sa1 = MFMA(a1, bw, sa1);
            }
            if (t < 64) {
                const int col = lane & 15;
                if (col < ND) {
#pragma unroll
                    for (int reg = 0; reg < 4; ++reg) {
                        sc_[(quad * 4 + reg) * 8 + col]      = sa0[reg];
                        sc_[(16 + quad * 4 + reg) * 8 + col] = sa1[reg];
                    }
                }
            }
        }
        __syncthreads();  // S5

        // ---- phase 6: dist_sq (full 32x32) ----
#pragma unroll
        for (int m = 0; m < 4; ++m) {
            const int p = t + 256 * m;
            const int i = p >> 5, j = p & 31;
            float s = 0.0f;
#pragma unroll
            for (int d = 0; d < ND; ++d) {
                const float df = Xs[i * 8 + d] - Xs[j * 8 + d];
                s += df * df;
            }
            ds_[p] = s;
        }
        __syncthreads();

        // ---- phase 7: unique pair list (i<j), 496 values ----
        for (int p = t; p < 496; p += 256) {
            int rem = p, i = 0;
            while (rem >= 31 - i) { rem -= 31 - i; ++i; }
            const int j = i + 1 + rem;
            ps_[p] = ds_[i * 32 + j];
        }
        __syncthreads();

        // ---- phase 8: exact median (rank 511 of 1024) by counting selection ----
        {
            const float cv0 = ps_[t];
            const float cv1 = (t < 240) ? ps_[t + 256] : 0.0f;
            int c0l = 0, c0e = 0, c1l = 0, c1e = 0;
            const float4* p4 = (const float4*)ps_;
#pragma unroll 2
            for (int u = 0; u < 124; ++u) {
                const float4 dv = p4[u];
                c0l += (dv.x < cv0) + (dv.y < cv0) + (dv.z < cv0) + (dv.w < cv0);
                c0e += (dv.x <= cv0) + (dv.y <= cv0) + (dv.z <= cv0) + (dv.w <= cv0);
                c1l += (dv.x < cv1) + (dv.y < cv1) + (dv.z < cv1) + (dv.w < cv1);
                c1e += (dv.x <= cv1) + (dv.y <= cv1) + (dv.z <= cv1) + (dv.w <= cv1);
            }
            int l = 2 * c0l + (cv0 > 0.0f ? 32 : 0);
            int e = 2 * c0e + 32;
            if (l <= 511 && 511 < e) med_s = cv0;
            l = 2 * c1l + (cv1 > 0.0f ? 32 : 0);
            e = 2 * c1e + 32;
            if (l <= 511 && 511 < e) med_s = cv1;
        }
        phiA[t] = 0.0f;
        __syncthreads();

        const float med = med_s;
        const float gam = 1.0f / (1e-8f + med / C_LOGNP1);

        // ---- phase 9: phi, line_4, line_5 partials ----
        {
            const int i = t & 31, jg = t >> 5;
            float ph[ND] = {0, 0, 0, 0, 0, 0};
            float l4p = 0.0f, l5p = 0.0f;
#pragma unroll
            for (int jj = 0; jj < 4; ++jj) {
                const int j = jg * 4 + jj;
                const float dsv = ds_[i * 32 + j];
                const float kap = __expf(-gam * dsv);
                const float tg = 2.0f * gam * kap;
                float dot = 0.0f;
#pragma unroll
                for (int d = 0; d < ND; ++d) {
                    const float df = Xs[i * 8 + d] - Xs[j * 8 + d];
                    const float sj = sc_[j * 8 + d];
                    ph[d] += kap * sj + tg * df;
                    dot += df * sj;
                }
                l4p += -tg * dot;
                l5p += tg * dsv - 6.0f * kap;
            }
#pragma unroll
            for (int d = 0; d < ND; ++d) atomicAdd(&phiA[i * 8 + d], ph[d]);
            atomicAdd(&phiA[i * 8 + 6], l4p);
            atomicAdd(&phiA[i * 8 + 7], l5p);
        }
        __syncthreads();

        // ---- phase 10: updates ----
        if (t < NP * ND) {
            const int i = t / ND, d = t - i * ND;
            const float phiv = phiA[i * 8 + d] * (1.0f / 32.0f);
            float x = Xs[i * 8 + d] + C_LR * phiv;
            x = fminf(fmaxf(x, -C_LIM), C_LIM);
            Xs[i * 8 + d] = x;
        } else if (t < NP * ND + NP) {
            const int i = t - NP * ND;
            const float l4 = phiA[i * 8 + 6] * (1.0f / 32.0f);
            const float l5 = -2.0f * gam * (phiA[i * 8 + 7] * (1.0f / 32.0f));
            logp_s[i] -= C_LR * (l4 + l5);
        }
        __syncthreads();
    }

    // ---- output: a (B*N, D) then logp (B, N) ----
    if (t < NP * ND) out[b * (NP * ND) + t] = Xs[(t / ND) * 8 + (t % ND)];
    if (t < NP) out[NB * NP * ND + b * NP + t] = logp_s[t];
}

extern "C" void kernel_launch(void* const* d_in, const int* in_sizes, int n_in,
                              void* d_out, int out_size, void* d_ws, size_t ws_size,
                              hipStream_t stream) {
    const float* obs = (const float*)d_in[0];
    const float* a   = (const float*)d_in[1];
    const float* W1  = (const float*)d_in[2];
    const float* b1  = (const float*)d_in[3];
    const float* W2  = (const float*)d_in[4];
    const float* b2  = (const float*)d_in[5];
    const float* W3  = (const float*)d_in[6];
    // d_in[7] = b3: unused (constant offset drops out of grad; q-values never output)
    unsigned short* wsu = (unsigned short*)d_ws;   // needs 270336 bytes
    float* out = (float*)d_out;

    prep_swizzle<<<66, 256, 0, stream>>>(W1, W2, wsu);
    svgd_kernel<<<NB, 256, 0, stream>>>(obs, a, W1, b1, W2, b2, W3, wsu, out);
}